// Round 6
// baseline (375.874 us; speedup 1.0000x reference)
//
#include <hip/hip_runtime.h>
#include <hip/hip_bf16.h>
#include <math.h>

// Problem constants (fixed by reference)
#define BATCH 2
#define SEQ   2048
#define DMODEL 2048
#define NHEADS 16
#define HDIM  128
#define MROWS (BATCH * SEQ)   // 4096

typedef __attribute__((ext_vector_type(8))) short short8;
typedef __attribute__((ext_vector_type(8))) unsigned short ushort8;
typedef __attribute__((ext_vector_type(4))) float f32x4;

static __device__ __forceinline__ unsigned short f2bf(float x) {
    __hip_bfloat16 h = __float2bfloat16(x);
    return __builtin_bit_cast(unsigned short, h);
}

static __device__ __forceinline__ void async_load16(const void* g, void* l) {
    __builtin_amdgcn_global_load_lds(
        (const __attribute__((address_space(1))) unsigned int*)g,
        (__attribute__((address_space(3))) unsigned int*)l, 16, 0, 0);
}

// ---------------------------------------------------------------------------
// fp32 -> bf16 elementwise convert (x)
// ---------------------------------------------------------------------------
__global__ __launch_bounds__(256) void convert_bf16_kernel(
    const float* __restrict__ in, unsigned short* __restrict__ out, int n)
{
    const int idx = (blockIdx.x * 256 + threadIdx.x) * 4;
    if (idx < n) {
        const float4 v = *(const float4*)(in + idx);
        ushort4 u;
        u.x = f2bf(v.x); u.y = f2bf(v.y); u.z = f2bf(v.z); u.w = f2bf(v.w);
        *(ushort4*)(out + idx) = u;
    }
}

// ---------------------------------------------------------------------------
// Fused transpose of wq,wk,wv: [K,N] fp32 -> [N,K] bf16 into 3 Wt slots.
// ---------------------------------------------------------------------------
__global__ __launch_bounds__(256) void transpose3_bf16_kernel(
    const float* __restrict__ w0, const float* __restrict__ w1,
    const float* __restrict__ w2, unsigned short* __restrict__ WtAll)
{
    const float* W = blockIdx.z == 0 ? w0 : (blockIdx.z == 1 ? w1 : w2);
    unsigned short* Wt = WtAll + (size_t)blockIdx.z * DMODEL * DMODEL;

    __shared__ float T[64][65];
    const int tid = threadIdx.x;
    const int tr  = tid >> 4;
    const int tc4 = (tid & 15) * 4;
    const int k0 = blockIdx.y * 64;
    const int n0 = blockIdx.x * 64;

    #pragma unroll
    for (int i = 0; i < 4; ++i) {
        const int kr = i * 16 + tr;
        const float4 v = *(const float4*)(W + (size_t)(k0 + kr) * DMODEL + n0 + tc4);
        T[kr][tc4 + 0] = v.x; T[kr][tc4 + 1] = v.y;
        T[kr][tc4 + 2] = v.z; T[kr][tc4 + 3] = v.w;
    }
    __syncthreads();
    #pragma unroll
    for (int i = 0; i < 4; ++i) {
        const int nr = i * 16 + tr;
        ushort4 u;
        u.x = f2bf(T[tc4 + 0][nr]); u.y = f2bf(T[tc4 + 1][nr]);
        u.z = f2bf(T[tc4 + 2][nr]); u.w = f2bf(T[tc4 + 3][nr]);
        *(ushort4*)(Wt + (size_t)(n0 + nr) * DMODEL + k0 + tc4) = u;
    }
}

// single transpose (for wo)
__global__ __launch_bounds__(256) void transpose_bf16_kernel(
    const float* __restrict__ W, unsigned short* __restrict__ Wt, int K, int N)
{
    __shared__ float T[64][65];
    const int tid = threadIdx.x;
    const int tr  = tid >> 4;
    const int tc4 = (tid & 15) * 4;
    const int k0 = blockIdx.y * 64;
    const int n0 = blockIdx.x * 64;

    #pragma unroll
    for (int i = 0; i < 4; ++i) {
        const int kr = i * 16 + tr;
        const float4 v = *(const float4*)(W + (size_t)(k0 + kr) * N + n0 + tc4);
        T[kr][tc4 + 0] = v.x; T[kr][tc4 + 1] = v.y;
        T[kr][tc4 + 2] = v.z; T[kr][tc4 + 3] = v.w;
    }
    __syncthreads();
    #pragma unroll
    for (int i = 0; i < 4; ++i) {
        const int nr = i * 16 + tr;
        ushort4 u;
        u.x = f2bf(T[tc4 + 0][nr]); u.y = f2bf(T[tc4 + 1][nr]);
        u.z = f2bf(T[tc4 + 2][nr]); u.w = f2bf(T[tc4 + 3][nr]);
        *(ushort4*)(Wt + (size_t)(n0 + nr) * K + k0 + tc4) = u;
    }
}

// ---------------------------------------------------------------------------
// Fused QKV GEMM — 128x128 tile, BK=32, 256 threads (4 waves, 2Mx2N).
// LDS = 32 KB -> 4 BLOCKS/CU (r5 proved block-residency is the lever:
// 1 blk/CU = 31% MfmaUtil, 2 blk/CU = 43%; per-CU LDS ceiling ~69%).
// 16 waves/CU (VGPR 88 < 128 so 4 waves/SIMD). Grid 1536 = 6 exact rounds.
// 2-phase counted-vmcnt: ph1 reads 8 frags + MFMA mt0-1; ph2 stages 4 units
// of tile t+2 + MFMA mt2-3; vmcnt(4) once per K-tile (8 in flight).
// Swizzle for 64B rows (4 granules x 16B): phys_granule = logical ^ m(row),
// m(r) = (r&3)^((r>>2)&3). Rows sharing a slot split across 2 banks ->
// 2-way max = free (m136). Applied involutively: pre-swizzled global source
// (linear gload_lds dest) + same XOR on ds_read (rule #21).
// XCD chunking by-inner: 4 concurrent same-bx blocks share each B-tile.
// ---------------------------------------------------------------------------
__global__ __launch_bounds__(256, 4) void qkv_gemm_bk32_kernel(
    const unsigned short* __restrict__ A, const unsigned short* __restrict__ WtAll,
    const float* __restrict__ bq, const float* __restrict__ bk,
    const float* __restrict__ bv,
    unsigned short* __restrict__ Qb, unsigned short* __restrict__ Kb,
    unsigned short* __restrict__ Vt)
{
    constexpr int K  = DMODEL;   // 2048
    constexpr int NT = K / 32;   // 64 K-tiles

    __shared__ __align__(16) unsigned short As[2][128 * 32];   // 8 KB each
    __shared__ __align__(16) unsigned short Bs[2][128 * 32];   // 8 KB each

    const int tid  = threadIdx.x;
    const int lane = tid & 63;
    const int wave = tid >> 6;      // 0..3
    const int ln15 = lane & 15;
    const int quad = lane >> 4;
    const int wr   = wave >> 1;     // 0..1  (M half)
    const int wc   = wave & 1;      // 0..1  (N half)

    // XCD chunking: 1536 blocks, 192/XCD; by-inner so 4 concurrent blocks
    // share a B-tile; XCD k owns by 4k..4k+3 (A band 2 MB, L2-resident).
    const int xcd = blockIdx.x & 7;
    const int loc = blockIdx.x >> 3;       // 0..191
    const int bx  = loc >> 2;              // 0..47  N tile
    const int by  = xcd * 4 + (loc & 3);   // 0..31  M tile
    const int bm  = by * 128;
    const int bn  = bx * 128;              // 0..6016
    const int widx = bn >> 11;             // 0=Q 1=K 2=V
    const int bnl  = bn & 2047;

    const float* bias = widx == 0 ? bq : (widx == 1 ? bk : bv);

    // ---- staging: thread -> (row sr in 64-row unit, swizzled src granule) ----
    const int sr  = tid >> 2;                            // 0..63
    const int sg  = (tid & 3) ^ (sr & 3) ^ ((sr >> 2) & 3);   // phys^m(sr)
    const unsigned short* Ag = A     + (size_t)(bm + sr) * K + sg * 8;
    const unsigned short* Bg = WtAll + (size_t)(bn + sr) * K + sg * 8;

    // ---- ds_read: physical granule = quad ^ m(row), row&15 == ln15 ----
    const int swz  = ((quad ^ (ln15 & 3) ^ ((ln15 >> 2) & 3))) * 8;
    const int arow = (wr * 64 + ln15) * 32;              // + mp*512
    const int brow = (wc * 64 + ln15) * 32;              // + np*512

#define STAGE_A(c, q, k0) async_load16(Ag + (size_t)(q) * 64 * K + (k0), \
                                       &As[c][(q) * 2048 + wave * 512])
#define STAGE_B(c, q, k0) async_load16(Bg + (size_t)(q) * 64 * K + (k0), \
                                       &Bs[c][(q) * 2048 + wave * 512])

    f32x4 acc[4][4];
    #pragma unroll
    for (int i = 0; i < 4; ++i)
        #pragma unroll
        for (int j = 0; j < 4; ++j) acc[i][j] = (f32x4){0.f, 0.f, 0.f, 0.f};

    // ---- prologue: tiles 0 and 1 fully staged (4 units each) ----
    STAGE_A(0, 0, 0);  STAGE_A(0, 1, 0);
    STAGE_B(0, 0, 0);  STAGE_B(0, 1, 0);
    STAGE_A(1, 0, 32); STAGE_A(1, 1, 32);
    STAGE_B(1, 0, 32); STAGE_B(1, 1, 32);
    asm volatile("s_waitcnt vmcnt(4)" ::: "memory");   // tile 0 landed
    __builtin_amdgcn_s_barrier();

    short8 af[4];
    short8 bfr[4];

    #pragma unroll 2
    for (int t = 0; t < NT; ++t) {
        const int c  = t & 1;
        const int k2 = (t + 2) * 32;
        const unsigned short* Ac = As[c];
        const unsigned short* Bc = Bs[c];

        // ---- phase 1: read all 8 frags; MFMA mt0-1 ----
        #pragma unroll
        for (int np = 0; np < 4; ++np)
            bfr[np] = *(const short8*)(Bc + brow + np * 512 + swz);
        #pragma unroll
        for (int mp = 0; mp < 4; ++mp)
            af[mp] = *(const short8*)(Ac + arow + mp * 512 + swz);
        __builtin_amdgcn_s_barrier();
        asm volatile("s_waitcnt lgkmcnt(0)" ::: "memory");
        __builtin_amdgcn_sched_barrier(0);
        __builtin_amdgcn_s_setprio(1);
        #pragma unroll
        for (int mt = 0; mt < 2; ++mt)
            #pragma unroll
            for (int nt = 0; nt < 4; ++nt)
                acc[mt][nt] = __builtin_amdgcn_mfma_f32_16x16x32_bf16(
                    af[mt], bfr[nt], acc[mt][nt], 0, 0, 0);
        __builtin_amdgcn_s_setprio(0);
        __builtin_amdgcn_s_barrier();

        // ---- phase 2: stage all 4 units of tile t+2; MFMA mt2-3 ----
        if (t + 2 < NT) {
            STAGE_A(c, 0, k2); STAGE_A(c, 1, k2);
            STAGE_B(c, 0, k2); STAGE_B(c, 1, k2);
        }
        __builtin_amdgcn_s_setprio(1);
        #pragma unroll
        for (int mt = 2; mt < 4; ++mt)
            #pragma unroll
            for (int nt = 0; nt < 4; ++nt)
                acc[mt][nt] = __builtin_amdgcn_mfma_f32_16x16x32_bf16(
                    af[mt], bfr[nt], acc[mt][nt], 0, 0, 0);
        __builtin_amdgcn_s_setprio(0);
        if (t + 2 < NT) { asm volatile("s_waitcnt vmcnt(4)" ::: "memory"); }
        else            { asm volatile("s_waitcnt vmcnt(0)" ::: "memory"); }
        __builtin_amdgcn_s_barrier();
    }

#undef STAGE_A
#undef STAGE_B

    // ---- epilogue ----
    if (widx == 2) {
        #pragma unroll
        for (int mp = 0; mp < 4; ++mp) {
            const int m0 = bm + wr * 64 + mp * 16 + quad * 4;
            const int bb = m0 >> 11;
            const int s0 = m0 & 2047;
            #pragma unroll
            for (int np = 0; np < 4; ++np) {
                const int col = bnl + wc * 64 + np * 16 + ln15;
                const float bvv = bias[col];
                ushort4 pk;
                pk.x = f2bf(acc[mp][np][0] + bvv);
                pk.y = f2bf(acc[mp][np][1] + bvv);
                pk.z = f2bf(acc[mp][np][2] + bvv);
                pk.w = f2bf(acc[mp][np][3] + bvv);
                *(ushort4*)(Vt + ((size_t)(bb * 16 + (col >> 7)) * 128 + (col & 127)) * SEQ + s0) = pk;
            }
        }
    } else {
        unsigned short* dst = widx ? Kb : Qb;
        #pragma unroll
        for (int mp = 0; mp < 4; ++mp)
            #pragma unroll
            for (int r = 0; r < 4; ++r) {
                const int row = bm + wr * 64 + mp * 16 + quad * 4 + r;
                #pragma unroll
                for (int np = 0; np < 4; ++np) {
                    const int col = bnl + wc * 64 + np * 16 + ln15;
                    dst[(size_t)row * DMODEL + col] = f2bf(acc[mp][np][r] + bias[col]);
                }
            }
    }
}

// ---------------------------------------------------------------------------
// Out-projection GEMM — exact clone of the round-5 proven qkv structure:
// 128x128, BK=64, 4 waves, LDS 64 KB -> 2 blocks/CU (43% MfmaUtil measured).
// Grid 16bx x 32by = 512 = exactly 2 rounds. fp32 epilogue + bias.
// ---------------------------------------------------------------------------
__global__ __launch_bounds__(256, 2) void gemm_out128_kernel(
    const unsigned short* __restrict__ A, const unsigned short* __restrict__ Bt,
    const float* __restrict__ bias, float* __restrict__ C)
{
    constexpr int K  = DMODEL;   // 2048
    constexpr int N  = DMODEL;   // 2048
    constexpr int NT = K / 64;   // 32 K-tiles

    __shared__ __align__(16) unsigned short As[2][128 * 64];   // 16 KB each
    __shared__ __align__(16) unsigned short Bs[2][128 * 64];   // 16 KB each

    const int tid  = threadIdx.x;
    const int lane = tid & 63;
    const int wave = tid >> 6;      // 0..3
    const int ln15 = lane & 15;
    const int quad = lane >> 4;
    const int wr   = wave >> 1;     // 0..1  (M half)
    const int wc   = wave & 1;      // 0..1  (N half)

    // XCD chunking: 512 blocks, 64/XCD; by-inner (4 blocks share a B-tile)
    const int xcd = blockIdx.x & 7;
    const int loc = blockIdx.x >> 3;       // 0..63
    const int bx  = loc >> 2;              // 0..15  N tile
    const int by  = xcd * 4 + (loc & 3);   // 0..31  M tile
    const int bm  = by * 128;
    const int bn  = bx * 128;

    const int sr = tid >> 3;                 // 0..31
    const int sg = (tid & 7) ^ (sr & 7);     // XOR swizzle (involution)
    const unsigned short* Ag = A  + (size_t)(bm + sr) * K + sg * 8;
    const unsigned short* Bg = Bt + (size_t)(bn + sr) * K + sg * 8;

    const int swz0 = ((0 + quad) ^ (ln15 & 7)) * 8;   // ks=0
    const int swz1 = ((4 + quad) ^ (ln15 & 7)) * 8;   // ks=1
    const int arow = (wr * 64 + ln15) * 64;
    const int brow = (wc * 64 + ln15) * 64;

#define STAGE_A(c, q, k0) async_load16(Ag + (size_t)(q) * 32 * K + (k0), \
                                       &As[c][(q) * 2048 + wave * 512])
#define STAGE_B(c, q, k0) async_load16(Bg + (size_t)(q) * 32 * K + (k0), \
                                       &Bs[c][(q) * 2048 + wave * 512])

    f32x4 acc[4][4];
    #pragma unroll
    for (int i = 0; i < 4; ++i)
        #pragma unroll
        for (int j = 0; j < 4; ++j) acc[i][j] = (f32x4){0.f, 0.f, 0.f, 0.f};

    STAGE_A(0, 0, 0); STAGE_A(0, 1, 0); STAGE_A(0, 2, 0); STAGE_A(0, 3, 0);
    STAGE_B(0, 0, 0); STAGE_B(0, 1, 0); STAGE_B(0, 2, 0); STAGE_B(0, 3, 0);
    STAGE_A(1, 0, 64); STAGE_A(1, 1, 64); STAGE_A(1, 2, 64); STAGE_A(1, 3, 64);
    STAGE_B(1, 0, 64); STAGE_B(1, 1, 64); STAGE_B(1, 2, 64); STAGE_B(1, 3, 64);
    asm volatile("s_waitcnt vmcnt(8)" ::: "memory");
    __builtin_amdgcn_s_barrier();

    short8 af[4][2];
    short8 bfr[4][2];

    #pragma unroll 2
    for (int t = 0; t < NT; ++t) {
        const int c  = t & 1;
        const int k2 = (t + 2) * 64;
        const unsigned short* Ac = As[c];
        const unsigned short* Bc = Bs[c];

        #pragma unroll
        for (int np = 0; np < 4; ++np) {
            bfr[np][0] = *(const short8*)(Bc + brow + np * 1024 + swz0);
            bfr[np][1] = *(const short8*)(Bc + brow + np * 1024 + swz1);
        }
        #pragma unroll
        for (int mp = 0; mp < 4; ++mp) {
            af[mp][0] = *(const short8*)(Ac + arow + mp * 1024 + swz0);
            af[mp][1] = *(const short8*)(Ac + arow + mp * 1024 + swz1);
        }
        __builtin_amdgcn_s_barrier();
        asm volatile("s_waitcnt lgkmcnt(0)" ::: "memory");
        __builtin_amdgcn_sched_barrier(0);
        __builtin_amdgcn_s_setprio(1);
        #pragma unroll
        for (int ks = 0; ks < 2; ++ks)
            #pragma unroll
            for (int mt = 0; mt < 2; ++mt)
                #pragma unroll
                for (int nt = 0; nt < 4; ++nt)
                    acc[mt][nt] = __builtin_amdgcn_mfma_f32_16x16x32_bf16(
                        af[mt][ks], bfr[nt][ks], acc[mt][nt], 0, 0, 0);
        __builtin_amdgcn_s_setprio(0);
        __builtin_amdgcn_s_barrier();

        if (t + 2 < NT) {
            STAGE_A(c, 0, k2); STAGE_A(c, 1, k2);
            STAGE_A(c, 2, k2); STAGE_A(c, 3, k2);
            STAGE_B(c, 0, k2); STAGE_B(c, 1, k2);
            STAGE_B(c, 2, k2); STAGE_B(c, 3, k2);
        }
        __builtin_amdgcn_s_setprio(1);
        #pragma unroll
        for (int ks = 0; ks < 2; ++ks)
            #pragma unroll
            for (int mt = 2; mt < 4; ++mt)
                #pragma unroll
                for (int nt = 0; nt < 4; ++nt)
                    acc[mt][nt] = __builtin_amdgcn_mfma_f32_16x16x32_bf16(
                        af[mt][ks], bfr[nt][ks], acc[mt][nt], 0, 0, 0);
        __builtin_amdgcn_s_setprio(0);
        if (t + 2 < NT) { asm volatile("s_waitcnt vmcnt(8)" ::: "memory"); }
        else            { asm volatile("s_waitcnt vmcnt(0)" ::: "memory"); }
        __builtin_amdgcn_s_barrier();
    }

#undef STAGE_A
#undef STAGE_B

    #pragma unroll
    for (int mp = 0; mp < 4; ++mp)
        #pragma unroll
        for (int r = 0; r < 4; ++r) {
            const int row = bm + wr * 64 + mp * 16 + quad * 4 + r;
            #pragma unroll
            for (int np = 0; np < 4; ++np) {
                const int col = bn + wc * 64 + np * 16 + ln15;
                C[(size_t)row * N + col] = acc[mp][np][r] + bias[col];
            }
        }
}

// ---------------------------------------------------------------------------
// MFMA flash attention — LDS-staged, double-buffered, fast-path/diagonal
// split, XCD-pinned. 1024 single-qblk blocks, 4 blocks/CU, per-CU-balanced
// qblk permutation (sum == 62 per CU slot). Unchanged from round 5.
// ---------------------------------------------------------------------------
#define ATT_P_STRIDE 40

__global__ __launch_bounds__(256, 4) void attn_kernel(
    const unsigned short* __restrict__ Qb, const unsigned short* __restrict__ Kb,
    const unsigned short* __restrict__ Vt,   // [B*H][HDIM][SEQ]
    unsigned short* __restrict__ O)
{
    __shared__ __align__(16) unsigned short Ks[2][32 * 128];
    __shared__ __align__(16) unsigned short Vs[2][128 * 32];
    __shared__ __align__(16) unsigned short Pl[4 * 16 * ATT_P_STRIDE];

    const int tid  = threadIdx.x;
    const int lane = tid & 63;
    const int wave = tid >> 6;
    const int ln15 = lane & 15;
    const int quad = lane >> 4;

    // XCD pinning + per-CU load balance
    const int g  = blockIdx.x & 31;
    const int j  = blockIdx.x >> 5;        // 0..31
    const int r_ = j >> 3;
    const int c_ = j & 7;
    const int qblk = r_ == 0 ? 31 - c_ : (r_ == 1 ? 16 + c_ : (r_ == 2 ? 15 - c_ : c_));
    const int h = g & 15;
    const int b = g >> 4;

    const size_t rowbase = (size_t)b * SEQ;
    const size_t hoff    = (size_t)h * HDIM;
    const unsigned short* Kh  = Kb + rowbase * DMODEL + hoff;
    const unsigned short* Vth = Vt + (size_t)(b * NHEADS + h) * HDIM * SEQ;

    const float sc2     = 0.08838834764831845f * 1.4426950408889634f;
    const float slope2  = exp2f(-0.5f * (float)(h + 1)) * 1.4426950408889634f;
    const float slope16 = slope2 * 16.0f;
    const float slope32 = slope2 * 32.0f;

    // staging lane roles
    const int kq  = wave * 8 + (lane >> 4);
    const int ksl = lane & 15;
    const int dq  = wave * 32 + (lane >> 2);
    const int vsl = lane & 3;
    const int vsw = (ln15 >> 1) & 3;

    unsigned short* Pw = &Pl[wave * 16 * ATT_P_STRIDE];

    const int q0w  = qblk * 64 + wave * 16;
    const int nT   = 2 * qblk + 2;

    short8 qf[4];
    {
        const unsigned short* qp =
            Qb + (rowbase + q0w + ln15) * DMODEL + hoff + quad * 8;
        qf[0] = *(const short8*)(qp);
        qf[1] = *(const short8*)(qp + 32);
        qf[2] = *(const short8*)(qp + 64);
        qf[3] = *(const short8*)(qp + 96);
    }

    f32x4 acc[8];
    #pragma unroll
    for (int nt = 0; nt < 8; ++nt) acc[nt] = (f32x4){0.f, 0.f, 0.f, 0.f};
    float lsum[4] = {0.f, 0.f, 0.f, 0.f};

    // incremental ALiBi bias: c0[r] = slope2*(kb+ln15 - (q0w+quad*4+r))
    float c0[4];
    {
        const float base = slope2 * (float)(ln15 - q0w - quad * 4);
        #pragma unroll
        for (int r = 0; r < 4; ++r) c0[r] = base - slope2 * (float)r;
    }

    // ---- stage tile 0 into buffer 0 ----
    #pragma unroll
    for (int i = 0; i < 2; ++i) {
        const int k = kq + i * 4;
        async_load16(Kh + (size_t)k * DMODEL + (ksl ^ (k & 15)) * 8,
                     &Ks[0][(wave * 8 + i * 4) * 128]);
    }
    #pragma unroll
    for (int i = 0; i < 2; ++i) {
        const int d = dq + i * 16;
        async_load16(Vth + (size_t)d * SEQ + (vsl ^ ((d >> 1) & 3)) * 8,
                     &Vs[0][(wave * 32 + i * 16) * 32]);
    }
    __syncthreads();

    for (int t = 0; t < nT; ++t) {
        const int kb  = t * 32;
        const int buf = t & 1;

        if (t + 1 < nT) {
            const int kb1 = kb + 32;
            #pragma unroll
            for (int i = 0; i < 2; ++i) {
                const int k = kq + i * 4;
                async_load16(Kh + (size_t)(kb1 + k) * DMODEL + (ksl ^ (k & 15)) * 8,
                             &Ks[buf ^ 1][(wave * 8 + i * 4) * 128]);
            }
            #pragma unroll
            for (int i = 0; i < 2; ++i) {
                const int d = dq + i * 16;
                async_load16(Vth + (size_t)d * SEQ + kb1 + (vsl ^ ((d >> 1) & 3)) * 8,
                             &Vs[buf ^ 1][(wave * 32 + i * 16) * 32]);
            }
        }

        if (kb <= q0w + 15) {
            const unsigned short* KsB = Ks[buf];
            const unsigned short* VsB = Vs[buf];

            f32x4 s0 = (f32x4){0.f,0.f,0.f,0.f}, s1 = (f32x4){0.f,0.f,0.f,0.f};
            #pragma unroll
            for (int c = 0; c < 4; ++c) {
                const int slot = (c * 4 + quad) ^ ln15;
                short8 kf0 = *(const short8*)(&KsB[ln15 * 128 + slot * 8]);
                short8 kf1 = *(const short8*)(&KsB[(16 + ln15) * 128 + slot * 8]);
                s0 = __builtin_amdgcn_mfma_f32_16x16x32_bf16(qf[c], kf0, s0, 0, 0, 0);
                s1 = __builtin_amdgcn_mfma_f32_16x16x32_bf16(qf[c], kf1, s1, 0, 0, 0);
            }

            float p0[4], p1[4];
            if (kb + 31 <= q0w) {
                // fully unmasked fast path
                #pragma unroll
                for (int r = 0; r < 4; ++r) {
                    p0[r] = exp2f(fmaf(s0[r], sc2, c0[r]));
                    p1[r] = exp2f(fmaf(s1[r], sc2, c0[r] + slope16));
                    lsum[r] += p0[r] + p1[r];
                }
            } else {
                // diagonal tile: per-element causal mask
                #pragma unroll
                for (int r = 0; r < 4; ++r) {
                    const int qrow = q0w + quad * 4 + r;
                    const int k0i = kb + ln15;
                    const float e0 = exp2f(fmaf(s0[r], sc2, c0[r]));
                    const float e1 = exp2f(fmaf(s1[r], sc2, c0[r] + slope16));
                    p0[r] = (k0i      <= qrow) ? e0 : 0.f;
                    p1[r] = (k0i + 16 <= qrow) ? e1 : 0.f;
                    lsum[r] += p0[r] + p1[r];
                }
            }

            #pragma unroll
            for (int r = 0; r < 4; ++r) {
                Pw[(quad * 4 + r) * ATT_P_STRIDE + ln15]      = f2bf(p0[r]);
                Pw[(quad * 4 + r) * ATT_P_STRIDE + 16 + ln15] = f2bf(p1[r]);
            }
            __builtin_amdgcn_s_waitcnt(0xC07F);   // lgkmcnt(0)
            short8 pf = *(const short8*)(&Pw[ln15 * ATT_P_STRIDE + quad * 8]);

            #pragma unroll
            for (int nt = 0; nt < 8; ++nt) {
                short8 vf = *(const short8*)(
                    &VsB[(nt * 16 + ln15) * 32 + (quad ^ vsw) * 8]);
                acc[nt] = __builtin_amdgcn_mfma_f32_16x16x32_bf16(pf, vf, acc[nt], 0, 0, 0);
            }
        }

        #pragma unroll
        for (int r = 0; r < 4; ++r) c0[r] += slope32;
        __syncthreads();
    }

    #pragma unroll
    for (int r = 0; r < 4; ++r) {
        float l = lsum[r];
        l += __shfl_xor(l, 1, 64);
        l += __shfl_xor(l, 2, 64);
        l += __shfl_xor(l, 4, 64);
        l += __shfl_xor(l, 8, 64);
        const float inv = 1.0f / l;
        const size_t ob = (rowbase + q0w + quad * 4 + r) * DMODEL + hoff;
        #pragma unroll
        for (int nt = 0; nt < 8; ++nt)
            O[ob + nt * 16 + ln15] = f2bf(acc[nt][r] * inv);
    }
}

// ---------------------------------------------------------------------------
extern "C" void kernel_launch(void* const* d_in, const int* in_sizes, int n_in,
                              void* d_out, int out_size, void* d_ws, size_t ws_size,
                              hipStream_t stream)
{
    const float* x  = (const float*)d_in[0];
    const float* wq = (const float*)d_in[1];
    const float* bq = (const float*)d_in[2];
    const float* wk = (const float*)d_in[3];
    const float* bk = (const float*)d_in[4];
    const float* wv = (const float*)d_in[5];
    const float* bv = (const float*)d_in[6];
    const float* wo = (const float*)d_in[7];
    const float* bo = (const float*)d_in[8];
    float* out = (float*)d_out;

    const size_t bufElems = (size_t)MROWS * DMODEL;   // 8.39M
    unsigned short* Qb  = (unsigned short*)d_ws;
    unsigned short* Kb  = Qb + bufElems;
    unsigned short* Vtg = Kb + bufElems;      // V^T: [B*H][HDIM][SEQ]
    unsigned short* xb  = Vtg + bufElems;     // x bf16; later reused as Ob
    unsigned short* Ob  = xb;                 // alias (xb dead after QKV GEMM)
    unsigned short* Wt  = xb + bufElems;      // 3 slots of 2048*2048 bf16

    const dim3 blk(256);

    convert_bf16_kernel<<<dim3((int)(bufElems / 1024)), blk, 0, stream>>>(
        x, xb, (int)bufElems);

    transpose3_bf16_kernel<<<dim3(32, 32, 3), blk, 0, stream>>>(wq, wk, wv, Wt);

    qkv_gemm_bk32_kernel<<<dim3(1536), dim3(256), 0, stream>>>(
        xb, Wt, bq, bk, bv, Qb, Kb, Vtg);

    // wo -> Wt slot 0 (QKV GEMM has consumed it by stream order)
    transpose_bf16_kernel<<<dim3(32, 32), blk, 0, stream>>>(wo, Wt, DMODEL, DMODEL);

    attn_kernel<<<dim3(1024), blk, 0, stream>>>(Qb, Kb, Vtg, Ob);

    gemm_out128_kernel<<<dim3(512), dim3(256), 0, stream>>>(
        Ob, Wt, bo, out);
}

// Round 7
// 358.248 us; speedup vs baseline: 1.0492x; 1.0492x over previous
//
#include <hip/hip_runtime.h>
#include <hip/hip_bf16.h>
#include <math.h>

// Problem constants (fixed by reference)
#define BATCH 2
#define SEQ   2048
#define DMODEL 2048
#define NHEADS 16
#define HDIM  128
#define MROWS (BATCH * SEQ)   // 4096

typedef __attribute__((ext_vector_type(8))) short short8;
typedef __attribute__((ext_vector_type(8))) unsigned short ushort8;
typedef __attribute__((ext_vector_type(4))) float f32x4;

static __device__ __forceinline__ unsigned short f2bf(float x) {
    __hip_bfloat16 h = __float2bfloat16(x);
    return __builtin_bit_cast(unsigned short, h);
}

static __device__ __forceinline__ void async_load16(const void* g, void* l) {
    __builtin_amdgcn_global_load_lds(
        (const __attribute__((address_space(1))) unsigned int*)g,
        (__attribute__((address_space(3))) unsigned int*)l, 16, 0, 0);
}

// ---------------------------------------------------------------------------
// fp32 -> bf16 elementwise convert (x)
// ---------------------------------------------------------------------------
__global__ __launch_bounds__(256) void convert_bf16_kernel(
    const float* __restrict__ in, unsigned short* __restrict__ out, int n)
{
    const int idx = (blockIdx.x * 256 + threadIdx.x) * 4;
    if (idx < n) {
        const float4 v = *(const float4*)(in + idx);
        ushort4 u;
        u.x = f2bf(v.x); u.y = f2bf(v.y); u.z = f2bf(v.z); u.w = f2bf(v.w);
        *(ushort4*)(out + idx) = u;
    }
}

// ---------------------------------------------------------------------------
// Fused transpose of wq,wk,wv: [K,N] fp32 -> [N,K] bf16 into 3 Wt slots.
// ---------------------------------------------------------------------------
__global__ __launch_bounds__(256) void transpose3_bf16_kernel(
    const float* __restrict__ w0, const float* __restrict__ w1,
    const float* __restrict__ w2, unsigned short* __restrict__ WtAll)
{
    const float* W = blockIdx.z == 0 ? w0 : (blockIdx.z == 1 ? w1 : w2);
    unsigned short* Wt = WtAll + (size_t)blockIdx.z * DMODEL * DMODEL;

    __shared__ float T[64][65];
    const int tid = threadIdx.x;
    const int tr  = tid >> 4;
    const int tc4 = (tid & 15) * 4;
    const int k0 = blockIdx.y * 64;
    const int n0 = blockIdx.x * 64;

    #pragma unroll
    for (int i = 0; i < 4; ++i) {
        const int kr = i * 16 + tr;
        const float4 v = *(const float4*)(W + (size_t)(k0 + kr) * DMODEL + n0 + tc4);
        T[kr][tc4 + 0] = v.x; T[kr][tc4 + 1] = v.y;
        T[kr][tc4 + 2] = v.z; T[kr][tc4 + 3] = v.w;
    }
    __syncthreads();
    #pragma unroll
    for (int i = 0; i < 4; ++i) {
        const int nr = i * 16 + tr;
        ushort4 u;
        u.x = f2bf(T[tc4 + 0][nr]); u.y = f2bf(T[tc4 + 1][nr]);
        u.z = f2bf(T[tc4 + 2][nr]); u.w = f2bf(T[tc4 + 3][nr]);
        *(ushort4*)(Wt + (size_t)(n0 + nr) * DMODEL + k0 + tc4) = u;
    }
}

// single transpose (for wo)
__global__ __launch_bounds__(256) void transpose_bf16_kernel(
    const float* __restrict__ W, unsigned short* __restrict__ Wt, int K, int N)
{
    __shared__ float T[64][65];
    const int tid = threadIdx.x;
    const int tr  = tid >> 4;
    const int tc4 = (tid & 15) * 4;
    const int k0 = blockIdx.y * 64;
    const int n0 = blockIdx.x * 64;

    #pragma unroll
    for (int i = 0; i < 4; ++i) {
        const int kr = i * 16 + tr;
        const float4 v = *(const float4*)(W + (size_t)(k0 + kr) * N + n0 + tc4);
        T[kr][tc4 + 0] = v.x; T[kr][tc4 + 1] = v.y;
        T[kr][tc4 + 2] = v.z; T[kr][tc4 + 3] = v.w;
    }
    __syncthreads();
    #pragma unroll
    for (int i = 0; i < 4; ++i) {
        const int nr = i * 16 + tr;
        ushort4 u;
        u.x = f2bf(T[tc4 + 0][nr]); u.y = f2bf(T[tc4 + 1][nr]);
        u.z = f2bf(T[tc4 + 2][nr]); u.w = f2bf(T[tc4 + 3][nr]);
        *(ushort4*)(Wt + (size_t)(n0 + nr) * K + k0 + tc4) = u;
    }
}

// ---------------------------------------------------------------------------
// Fused QKV GEMM — 128x128 tile, BK=64, 256 threads (4 waves, 2Mx2N).
// EXACT round-5 kernel (105.3 us, MfmaUtil 43%, conflicts 0). r6's BK=32
// variant regressed (132 us, 1.26e7 conflicts): 64-B LDS rows give only 8
// four-bank groups -> 8 lanes/group for wave64 b128 reads; NO granule
// permutation can fix that. Constraint recorded: b128 column-fragment reads
// need >=128-B LDS rows (BK>=64 for bf16).
// LDS = 64 KB -> 2 blocks/CU. Grid 1536 = 6 exact rounds.
// ---------------------------------------------------------------------------
__global__ __launch_bounds__(256, 2) void qkv_gemm128_kernel(
    const unsigned short* __restrict__ A, const unsigned short* __restrict__ WtAll,
    const float* __restrict__ bq, const float* __restrict__ bk,
    const float* __restrict__ bv,
    unsigned short* __restrict__ Qb, unsigned short* __restrict__ Kb,
    unsigned short* __restrict__ Vt)
{
    constexpr int K  = DMODEL;   // 2048
    constexpr int NT = K / 64;   // 32 K-tiles

    __shared__ __align__(16) unsigned short As[2][128 * 64];   // 16 KB each
    __shared__ __align__(16) unsigned short Bs[2][128 * 64];   // 16 KB each

    const int tid  = threadIdx.x;
    const int lane = tid & 63;
    const int wave = tid >> 6;      // 0..3
    const int ln15 = lane & 15;
    const int quad = lane >> 4;
    const int wr   = wave >> 1;     // 0..1  (M half)
    const int wc   = wave & 1;      // 0..1  (N half)

    // XCD chunking: 1536 blocks, 192/XCD; by-inner so 4 concurrent blocks
    // share a B-tile; XCD k owns by 4k..4k+3 (A band 2 MB, L2-resident).
    const int xcd = blockIdx.x & 7;
    const int loc = blockIdx.x >> 3;       // 0..191
    const int bx  = loc >> 2;              // 0..47  N tile
    const int by  = xcd * 4 + (loc & 3);   // 0..31  M tile
    const int bm  = by * 128;
    const int bn  = bx * 128;              // 0..6016
    const int widx = bn >> 11;             // 0=Q 1=K 2=V
    const int bnl  = bn & 2047;

    const float* bias = widx == 0 ? bq : (widx == 1 ? bk : bv);

    // ---- staging: thread -> (row sr within 32-row unit, swizzled granule) ----
    const int sr = tid >> 3;                 // 0..31
    const int sg = (tid & 7) ^ (sr & 7);     // XOR swizzle (involution)
    const unsigned short* Ag = A     + (size_t)(bm + sr) * K + sg * 8;
    const unsigned short* Bg = WtAll + (size_t)(bn + sr) * K + sg * 8;

    // ---- ds_read offsets (ushort units); physical granule = logical ^ (row&7)
    const int swz0 = ((0 + quad) ^ (ln15 & 7)) * 8;   // ks=0
    const int swz1 = ((4 + quad) ^ (ln15 & 7)) * 8;   // ks=1
    const int arow = (wr * 64 + ln15) * 64;           // + mp*1024
    const int brow = (wc * 64 + ln15) * 64;           // + np*1024

#define STAGE_A(c, q, k0) async_load16(Ag + (size_t)(q) * 32 * K + (k0), \
                                       &As[c][(q) * 2048 + wave * 512])
#define STAGE_B(c, q, k0) async_load16(Bg + (size_t)(q) * 32 * K + (k0), \
                                       &Bs[c][(q) * 2048 + wave * 512])

    f32x4 acc[4][4];
    #pragma unroll
    for (int i = 0; i < 4; ++i)
        #pragma unroll
        for (int j = 0; j < 4; ++j) acc[i][j] = (f32x4){0.f, 0.f, 0.f, 0.f};

    // ---- prologue: tiles 0 and 1 fully staged (8 units each) ----
    STAGE_A(0, 0, 0); STAGE_A(0, 1, 0); STAGE_A(0, 2, 0); STAGE_A(0, 3, 0);
    STAGE_B(0, 0, 0); STAGE_B(0, 1, 0); STAGE_B(0, 2, 0); STAGE_B(0, 3, 0);
    STAGE_A(1, 0, 64); STAGE_A(1, 1, 64); STAGE_A(1, 2, 64); STAGE_A(1, 3, 64);
    STAGE_B(1, 0, 64); STAGE_B(1, 1, 64); STAGE_B(1, 2, 64); STAGE_B(1, 3, 64);
    asm volatile("s_waitcnt vmcnt(8)" ::: "memory");   // tile 0 landed
    __builtin_amdgcn_s_barrier();

    short8 af[4][2];
    short8 bfr[4][2];

    #pragma unroll 2
    for (int t = 0; t < NT; ++t) {
        const int c  = t & 1;
        const int k2 = (t + 2) * 64;
        const unsigned short* Ac = As[c];
        const unsigned short* Bc = Bs[c];

        // ---- phase 1: read ALL 16 frags; MFMA mt0-1 ----
        #pragma unroll
        for (int np = 0; np < 4; ++np) {
            bfr[np][0] = *(const short8*)(Bc + brow + np * 1024 + swz0);
            bfr[np][1] = *(const short8*)(Bc + brow + np * 1024 + swz1);
        }
        #pragma unroll
        for (int mp = 0; mp < 4; ++mp) {
            af[mp][0] = *(const short8*)(Ac + arow + mp * 1024 + swz0);
            af[mp][1] = *(const short8*)(Ac + arow + mp * 1024 + swz1);
        }
        __builtin_amdgcn_s_barrier();
        asm volatile("s_waitcnt lgkmcnt(0)" ::: "memory");
        __builtin_amdgcn_sched_barrier(0);
        __builtin_amdgcn_s_setprio(1);
        #pragma unroll
        for (int ks = 0; ks < 2; ++ks)
            #pragma unroll
            for (int mt = 0; mt < 2; ++mt)
                #pragma unroll
                for (int nt = 0; nt < 4; ++nt)
                    acc[mt][nt] = __builtin_amdgcn_mfma_f32_16x16x32_bf16(
                        af[mt][ks], bfr[nt][ks], acc[mt][nt], 0, 0, 0);
        __builtin_amdgcn_s_setprio(0);
        __builtin_amdgcn_s_barrier();

        // ---- phase 2: stage all 8 units of tile t+2; MFMA mt2-3 ----
        if (t + 2 < NT) {
            STAGE_A(c, 0, k2); STAGE_A(c, 1, k2);
            STAGE_A(c, 2, k2); STAGE_A(c, 3, k2);
            STAGE_B(c, 0, k2); STAGE_B(c, 1, k2);
            STAGE_B(c, 2, k2); STAGE_B(c, 3, k2);
        }
        __builtin_amdgcn_s_setprio(1);
        #pragma unroll
        for (int ks = 0; ks < 2; ++ks)
            #pragma unroll
            for (int mt = 2; mt < 4; ++mt)
                #pragma unroll
                for (int nt = 0; nt < 4; ++nt)
                    acc[mt][nt] = __builtin_amdgcn_mfma_f32_16x16x32_bf16(
                        af[mt][ks], bfr[nt][ks], acc[mt][nt], 0, 0, 0);
        __builtin_amdgcn_s_setprio(0);
        if (t + 2 < NT) { asm volatile("s_waitcnt vmcnt(8)" ::: "memory"); }
        else            { asm volatile("s_waitcnt vmcnt(0)" ::: "memory"); }
        __builtin_amdgcn_s_barrier();
    }

#undef STAGE_A
#undef STAGE_B

    // ---- epilogue ----
    if (widx == 2) {
        #pragma unroll
        for (int mp = 0; mp < 4; ++mp) {
            const int m0 = bm + wr * 64 + mp * 16 + quad * 4;
            const int bb = m0 >> 11;
            const int s0 = m0 & 2047;
            #pragma unroll
            for (int np = 0; np < 4; ++np) {
                const int col = bnl + wc * 64 + np * 16 + ln15;
                const float bvv = bias[col];
                ushort4 pk;
                pk.x = f2bf(acc[mp][np][0] + bvv);
                pk.y = f2bf(acc[mp][np][1] + bvv);
                pk.z = f2bf(acc[mp][np][2] + bvv);
                pk.w = f2bf(acc[mp][np][3] + bvv);
                *(ushort4*)(Vt + ((size_t)(bb * 16 + (col >> 7)) * 128 + (col & 127)) * SEQ + s0) = pk;
            }
        }
    } else {
        unsigned short* dst = widx ? Kb : Qb;
        #pragma unroll
        for (int mp = 0; mp < 4; ++mp)
            #pragma unroll
            for (int r = 0; r < 4; ++r) {
                const int row = bm + wr * 64 + mp * 16 + quad * 4 + r;
                #pragma unroll
                for (int np = 0; np < 4; ++np) {
                    const int col = bnl + wc * 64 + np * 16 + ln15;
                    dst[(size_t)row * DMODEL + col] = f2bf(acc[mp][np][r] + bias[col]);
                }
            }
    }
}

// ---------------------------------------------------------------------------
// Out-projection GEMM — 128x128, BK=64, 4 waves, LDS 64 KB -> 2 blocks/CU.
// Kept from round 6 (rest-of-pipeline dropped 23 us vs gemm_out256).
// Grid 512 = exactly 2 rounds. fp32 epilogue + bias.
// ---------------------------------------------------------------------------
__global__ __launch_bounds__(256, 2) void gemm_out128_kernel(
    const unsigned short* __restrict__ A, const unsigned short* __restrict__ Bt,
    const float* __restrict__ bias, float* __restrict__ C)
{
    constexpr int K  = DMODEL;   // 2048
    constexpr int N  = DMODEL;   // 2048
    constexpr int NT = K / 64;   // 32 K-tiles

    __shared__ __align__(16) unsigned short As[2][128 * 64];   // 16 KB each
    __shared__ __align__(16) unsigned short Bs[2][128 * 64];   // 16 KB each

    const int tid  = threadIdx.x;
    const int lane = tid & 63;
    const int wave = tid >> 6;      // 0..3
    const int ln15 = lane & 15;
    const int quad = lane >> 4;
    const int wr   = wave >> 1;     // 0..1  (M half)
    const int wc   = wave & 1;      // 0..1  (N half)

    // XCD chunking: 512 blocks, 64/XCD; by-inner (4 blocks share a B-tile)
    const int xcd = blockIdx.x & 7;
    const int loc = blockIdx.x >> 3;       // 0..63
    const int bx  = loc >> 2;              // 0..15  N tile
    const int by  = xcd * 4 + (loc & 3);   // 0..31  M tile
    const int bm  = by * 128;
    const int bn  = bx * 128;

    const int sr = tid >> 3;                 // 0..31
    const int sg = (tid & 7) ^ (sr & 7);     // XOR swizzle (involution)
    const unsigned short* Ag = A  + (size_t)(bm + sr) * K + sg * 8;
    const unsigned short* Bg = Bt + (size_t)(bn + sr) * K + sg * 8;

    const int swz0 = ((0 + quad) ^ (ln15 & 7)) * 8;   // ks=0
    const int swz1 = ((4 + quad) ^ (ln15 & 7)) * 8;   // ks=1
    const int arow = (wr * 64 + ln15) * 64;
    const int brow = (wc * 64 + ln15) * 64;

#define STAGE_A(c, q, k0) async_load16(Ag + (size_t)(q) * 32 * K + (k0), \
                                       &As[c][(q) * 2048 + wave * 512])
#define STAGE_B(c, q, k0) async_load16(Bg + (size_t)(q) * 32 * K + (k0), \
                                       &Bs[c][(q) * 2048 + wave * 512])

    f32x4 acc[4][4];
    #pragma unroll
    for (int i = 0; i < 4; ++i)
        #pragma unroll
        for (int j = 0; j < 4; ++j) acc[i][j] = (f32x4){0.f, 0.f, 0.f, 0.f};

    STAGE_A(0, 0, 0); STAGE_A(0, 1, 0); STAGE_A(0, 2, 0); STAGE_A(0, 3, 0);
    STAGE_B(0, 0, 0); STAGE_B(0, 1, 0); STAGE_B(0, 2, 0); STAGE_B(0, 3, 0);
    STAGE_A(1, 0, 64); STAGE_A(1, 1, 64); STAGE_A(1, 2, 64); STAGE_A(1, 3, 64);
    STAGE_B(1, 0, 64); STAGE_B(1, 1, 64); STAGE_B(1, 2, 64); STAGE_B(1, 3, 64);
    asm volatile("s_waitcnt vmcnt(8)" ::: "memory");
    __builtin_amdgcn_s_barrier();

    short8 af[4][2];
    short8 bfr[4][2];

    #pragma unroll 2
    for (int t = 0; t < NT; ++t) {
        const int c  = t & 1;
        const int k2 = (t + 2) * 64;
        const unsigned short* Ac = As[c];
        const unsigned short* Bc = Bs[c];

        #pragma unroll
        for (int np = 0; np < 4; ++np) {
            bfr[np][0] = *(const short8*)(Bc + brow + np * 1024 + swz0);
            bfr[np][1] = *(const short8*)(Bc + brow + np * 1024 + swz1);
        }
        #pragma unroll
        for (int mp = 0; mp < 4; ++mp) {
            af[mp][0] = *(const short8*)(Ac + arow + mp * 1024 + swz0);
            af[mp][1] = *(const short8*)(Ac + arow + mp * 1024 + swz1);
        }
        __builtin_amdgcn_s_barrier();
        asm volatile("s_waitcnt lgkmcnt(0)" ::: "memory");
        __builtin_amdgcn_sched_barrier(0);
        __builtin_amdgcn_s_setprio(1);
        #pragma unroll
        for (int ks = 0; ks < 2; ++ks)
            #pragma unroll
            for (int mt = 0; mt < 2; ++mt)
                #pragma unroll
                for (int nt = 0; nt < 4; ++nt)
                    acc[mt][nt] = __builtin_amdgcn_mfma_f32_16x16x32_bf16(
                        af[mt][ks], bfr[nt][ks], acc[mt][nt], 0, 0, 0);
        __builtin_amdgcn_s_setprio(0);
        __builtin_amdgcn_s_barrier();

        if (t + 2 < NT) {
            STAGE_A(c, 0, k2); STAGE_A(c, 1, k2);
            STAGE_A(c, 2, k2); STAGE_A(c, 3, k2);
            STAGE_B(c, 0, k2); STAGE_B(c, 1, k2);
            STAGE_B(c, 2, k2); STAGE_B(c, 3, k2);
        }
        __builtin_amdgcn_s_setprio(1);
        #pragma unroll
        for (int ks = 0; ks < 2; ++ks)
            #pragma unroll
            for (int mt = 2; mt < 4; ++mt)
                #pragma unroll
                for (int nt = 0; nt < 4; ++nt)
                    acc[mt][nt] = __builtin_amdgcn_mfma_f32_16x16x32_bf16(
                        af[mt][ks], bfr[nt][ks], acc[mt][nt], 0, 0, 0);
        __builtin_amdgcn_s_setprio(0);
        if (t + 2 < NT) { asm volatile("s_waitcnt vmcnt(8)" ::: "memory"); }
        else            { asm volatile("s_waitcnt vmcnt(0)" ::: "memory"); }
        __builtin_amdgcn_s_barrier();
    }

#undef STAGE_A
#undef STAGE_B

    #pragma unroll
    for (int mp = 0; mp < 4; ++mp)
        #pragma unroll
        for (int r = 0; r < 4; ++r) {
            const int row = bm + wr * 64 + mp * 16 + quad * 4 + r;
            #pragma unroll
            for (int np = 0; np < 4; ++np) {
                const int col = bn + wc * 64 + np * 16 + ln15;
                C[(size_t)row * N + col] = acc[mp][np][r] + bias[col];
            }
        }
}

// ---------------------------------------------------------------------------
// MFMA flash attention — LDS-staged, double-buffered, fast-path/diagonal
// split, XCD-pinned. 1024 single-qblk blocks, 4 blocks/CU, per-CU-balanced
// qblk permutation (sum == 62 per CU slot). Unchanged from round 5.
// ---------------------------------------------------------------------------
#define ATT_P_STRIDE 40

__global__ __launch_bounds__(256, 4) void attn_kernel(
    const unsigned short* __restrict__ Qb, const unsigned short* __restrict__ Kb,
    const unsigned short* __restrict__ Vt,   // [B*H][HDIM][SEQ]
    unsigned short* __restrict__ O)
{
    __shared__ __align__(16) unsigned short Ks[2][32 * 128];
    __shared__ __align__(16) unsigned short Vs[2][128 * 32];
    __shared__ __align__(16) unsigned short Pl[4 * 16 * ATT_P_STRIDE];

    const int tid  = threadIdx.x;
    const int lane = tid & 63;
    const int wave = tid >> 6;
    const int ln15 = lane & 15;
    const int quad = lane >> 4;

    // XCD pinning + per-CU load balance
    const int g  = blockIdx.x & 31;
    const int j  = blockIdx.x >> 5;        // 0..31
    const int r_ = j >> 3;
    const int c_ = j & 7;
    const int qblk = r_ == 0 ? 31 - c_ : (r_ == 1 ? 16 + c_ : (r_ == 2 ? 15 - c_ : c_));
    const int h = g & 15;
    const int b = g >> 4;

    const size_t rowbase = (size_t)b * SEQ;
    const size_t hoff    = (size_t)h * HDIM;
    const unsigned short* Kh  = Kb + rowbase * DMODEL + hoff;
    const unsigned short* Vth = Vt + (size_t)(b * NHEADS + h) * HDIM * SEQ;

    const float sc2     = 0.08838834764831845f * 1.4426950408889634f;
    const float slope2  = exp2f(-0.5f * (float)(h + 1)) * 1.4426950408889634f;
    const float slope16 = slope2 * 16.0f;
    const float slope32 = slope2 * 32.0f;

    // staging lane roles
    const int kq  = wave * 8 + (lane >> 4);
    const int ksl = lane & 15;
    const int dq  = wave * 32 + (lane >> 2);
    const int vsl = lane & 3;
    const int vsw = (ln15 >> 1) & 3;

    unsigned short* Pw = &Pl[wave * 16 * ATT_P_STRIDE];

    const int q0w  = qblk * 64 + wave * 16;
    const int nT   = 2 * qblk + 2;

    short8 qf[4];
    {
        const unsigned short* qp =
            Qb + (rowbase + q0w + ln15) * DMODEL + hoff + quad * 8;
        qf[0] = *(const short8*)(qp);
        qf[1] = *(const short8*)(qp + 32);
        qf[2] = *(const short8*)(qp + 64);
        qf[3] = *(const short8*)(qp + 96);
    }

    f32x4 acc[8];
    #pragma unroll
    for (int nt = 0; nt < 8; ++nt) acc[nt] = (f32x4){0.f, 0.f, 0.f, 0.f};
    float lsum[4] = {0.f, 0.f, 0.f, 0.f};

    // incremental ALiBi bias: c0[r] = slope2*(kb+ln15 - (q0w+quad*4+r))
    float c0[4];
    {
        const float base = slope2 * (float)(ln15 - q0w - quad * 4);
        #pragma unroll
        for (int r = 0; r < 4; ++r) c0[r] = base - slope2 * (float)r;
    }

    // ---- stage tile 0 into buffer 0 ----
    #pragma unroll
    for (int i = 0; i < 2; ++i) {
        const int k = kq + i * 4;
        async_load16(Kh + (size_t)k * DMODEL + (ksl ^ (k & 15)) * 8,
                     &Ks[0][(wave * 8 + i * 4) * 128]);
    }
    #pragma unroll
    for (int i = 0; i < 2; ++i) {
        const int d = dq + i * 16;
        async_load16(Vth + (size_t)d * SEQ + (vsl ^ ((d >> 1) & 3)) * 8,
                     &Vs[0][(wave * 32 + i * 16) * 32]);
    }
    __syncthreads();

    for (int t = 0; t < nT; ++t) {
        const int kb  = t * 32;
        const int buf = t & 1;

        if (t + 1 < nT) {
            const int kb1 = kb + 32;
            #pragma unroll
            for (int i = 0; i < 2; ++i) {
                const int k = kq + i * 4;
                async_load16(Kh + (size_t)(kb1 + k) * DMODEL + (ksl ^ (k & 15)) * 8,
                             &Ks[buf ^ 1][(wave * 8 + i * 4) * 128]);
            }
            #pragma unroll
            for (int i = 0; i < 2; ++i) {
                const int d = dq + i * 16;
                async_load16(Vth + (size_t)d * SEQ + kb1 + (vsl ^ ((d >> 1) & 3)) * 8,
                             &Vs[buf ^ 1][(wave * 32 + i * 16) * 32]);
            }
        }

        if (kb <= q0w + 15) {
            const unsigned short* KsB = Ks[buf];
            const unsigned short* VsB = Vs[buf];

            f32x4 s0 = (f32x4){0.f,0.f,0.f,0.f}, s1 = (f32x4){0.f,0.f,0.f,0.f};
            #pragma unroll
            for (int c = 0; c < 4; ++c) {
                const int slot = (c * 4 + quad) ^ ln15;
                short8 kf0 = *(const short8*)(&KsB[ln15 * 128 + slot * 8]);
                short8 kf1 = *(const short8*)(&KsB[(16 + ln15) * 128 + slot * 8]);
                s0 = __builtin_amdgcn_mfma_f32_16x16x32_bf16(qf[c], kf0, s0, 0, 0, 0);
                s1 = __builtin_amdgcn_mfma_f32_16x16x32_bf16(qf[c], kf1, s1, 0, 0, 0);
            }

            float p0[4], p1[4];
            if (kb + 31 <= q0w) {
                // fully unmasked fast path
                #pragma unroll
                for (int r = 0; r < 4; ++r) {
                    p0[r] = exp2f(fmaf(s0[r], sc2, c0[r]));
                    p1[r] = exp2f(fmaf(s1[r], sc2, c0[r] + slope16));
                    lsum[r] += p0[r] + p1[r];
                }
            } else {
                // diagonal tile: per-element causal mask
                #pragma unroll
                for (int r = 0; r < 4; ++r) {
                    const int qrow = q0w + quad * 4 + r;
                    const int k0i = kb + ln15;
                    const float e0 = exp2f(fmaf(s0[r], sc2, c0[r]));
                    const float e1 = exp2f(fmaf(s1[r], sc2, c0[r] + slope16));
                    p0[r] = (k0i      <= qrow) ? e0 : 0.f;
                    p1[r] = (k0i + 16 <= qrow) ? e1 : 0.f;
                    lsum[r] += p0[r] + p1[r];
                }
            }

            #pragma unroll
            for (int r = 0; r < 4; ++r) {
                Pw[(quad * 4 + r) * ATT_P_STRIDE + ln15]      = f2bf(p0[r]);
                Pw[(quad * 4 + r) * ATT_P_STRIDE + 16 + ln15] = f2bf(p1[r]);
            }
            __builtin_amdgcn_s_waitcnt(0xC07F);   // lgkmcnt(0)
            short8 pf = *(const short8*)(&Pw[ln15 * ATT_P_STRIDE + quad * 8]);

            #pragma unroll
            for (int nt = 0; nt < 8; ++nt) {
                short8 vf = *(const short8*)(
                    &VsB[(nt * 16 + ln15) * 32 + (quad ^ vsw) * 8]);
                acc[nt] = __builtin_amdgcn_mfma_f32_16x16x32_bf16(pf, vf, acc[nt], 0, 0, 0);
            }
        }

        #pragma unroll
        for (int r = 0; r < 4; ++r) c0[r] += slope32;
        __syncthreads();
    }

    #pragma unroll
    for (int r = 0; r < 4; ++r) {
        float l = lsum[r];
        l += __shfl_xor(l, 1, 64);
        l += __shfl_xor(l, 2, 64);
        l += __shfl_xor(l, 4, 64);
        l += __shfl_xor(l, 8, 64);
        const float inv = 1.0f / l;
        const size_t ob = (rowbase + q0w + quad * 4 + r) * DMODEL + hoff;
        #pragma unroll
        for (int nt = 0; nt < 8; ++nt)
            O[ob + nt * 16 + ln15] = f2bf(acc[nt][r] * inv);
    }
}

// ---------------------------------------------------------------------------
extern "C" void kernel_launch(void* const* d_in, const int* in_sizes, int n_in,
                              void* d_out, int out_size, void* d_ws, size_t ws_size,
                              hipStream_t stream)
{
    const float* x  = (const float*)d_in[0];
    const float* wq = (const float*)d_in[1];
    const float* bq = (const float*)d_in[2];
    const float* wk = (const float*)d_in[3];
    const float* bk = (const float*)d_in[4];
    const float* wv = (const float*)d_in[5];
    const float* bv = (const float*)d_in[6];
    const float* wo = (const float*)d_in[7];
    const float* bo = (const float*)d_in[8];
    float* out = (float*)d_out;

    const size_t bufElems = (size_t)MROWS * DMODEL;   // 8.39M
    unsigned short* Qb  = (unsigned short*)d_ws;
    unsigned short* Kb  = Qb + bufElems;
    unsigned short* Vtg = Kb + bufElems;      // V^T: [B*H][HDIM][SEQ]
    unsigned short* xb  = Vtg + bufElems;     // x bf16; later reused as Ob
    unsigned short* Ob  = xb;                 // alias (xb dead after QKV GEMM)
    unsigned short* Wt  = xb + bufElems;      // 3 slots of 2048*2048 bf16

    const dim3 blk(256);

    convert_bf16_kernel<<<dim3((int)(bufElems / 1024)), blk, 0, stream>>>(
        x, xb, (int)bufElems);

    transpose3_bf16_kernel<<<dim3(32, 32, 3), blk, 0, stream>>>(wq, wk, wv, Wt);

    qkv_gemm128_kernel<<<dim3(1536), dim3(256), 0, stream>>>(
        xb, Wt, bq, bk, bv, Qb, Kb, Vtg);

    // wo -> Wt slot 0 (QKV GEMM has consumed it by stream order)
    transpose_bf16_kernel<<<dim3(32, 32), blk, 0, stream>>>(wo, Wt, DMODEL, DMODEL);

    attn_kernel<<<dim3(1024), blk, 0, stream>>>(Qb, Kb, Vtg, Ob);

    gemm_out128_kernel<<<dim3(512), dim3(256), 0, stream>>>(
        Ob, Wt, bo, out);
}

// Round 8
// 348.531 us; speedup vs baseline: 1.0785x; 1.0279x over previous
//
#include <hip/hip_runtime.h>
#include <hip/hip_bf16.h>
#include <math.h>

// Problem constants (fixed by reference)
#define BATCH 2
#define SEQ   2048
#define DMODEL 2048
#define NHEADS 16
#define HDIM  128
#define MROWS (BATCH * SEQ)   // 4096

typedef __attribute__((ext_vector_type(8))) short short8;
typedef __attribute__((ext_vector_type(8))) unsigned short ushort8;
typedef __attribute__((ext_vector_type(4))) float f32x4;

static __device__ __forceinline__ unsigned short f2bf(float x) {
    __hip_bfloat16 h = __float2bfloat16(x);
    return __builtin_bit_cast(unsigned short, h);
}

static __device__ __forceinline__ void async_load16(const void* g, void* l) {
    __builtin_amdgcn_global_load_lds(
        (const __attribute__((address_space(1))) unsigned int*)g,
        (__attribute__((address_space(3))) unsigned int*)l, 16, 0, 0);
}

// ---------------------------------------------------------------------------
// Fused prep: one dispatch replaces convert_bf16 + transpose3 + transpose_wo.
//  blocks 0..4095   : transpose slot z = bid>>10 (wq,wk,wv,wo -> Wt slots 0-3)
//  blocks 4096..12287: fp32 -> bf16 convert of x (4 elems/thread)
// Removes 2 launch gaps per iteration and the transpose_wo serialization
// point that sat between qkv and attn; all prep work fills the GPU at once.
// ---------------------------------------------------------------------------
__global__ __launch_bounds__(256) void prep_kernel(
    const float* __restrict__ x,
    const float* __restrict__ wq, const float* __restrict__ wk,
    const float* __restrict__ wv, const float* __restrict__ wo,
    unsigned short* __restrict__ xb, unsigned short* __restrict__ WtAll)
{
    const int bid = blockIdx.x;
    const int tid = threadIdx.x;

    if (bid < 4096) {
        // ---- weight transpose: [K,N] fp32 -> [N,K] bf16 ----
        const int z  = bid >> 10;
        const int r  = bid & 1023;
        const int bx = r & 31;
        const int by = r >> 5;
        const float* W = z == 0 ? wq : (z == 1 ? wk : (z == 2 ? wv : wo));
        unsigned short* Wt = WtAll + (size_t)z * DMODEL * DMODEL;

        __shared__ float T[64][65];
        const int tr  = tid >> 4;
        const int tc4 = (tid & 15) * 4;
        const int k0 = by * 64;
        const int n0 = bx * 64;

        #pragma unroll
        for (int i = 0; i < 4; ++i) {
            const int kr = i * 16 + tr;
            const float4 v = *(const float4*)(W + (size_t)(k0 + kr) * DMODEL + n0 + tc4);
            T[kr][tc4 + 0] = v.x; T[kr][tc4 + 1] = v.y;
            T[kr][tc4 + 2] = v.z; T[kr][tc4 + 3] = v.w;
        }
        __syncthreads();
        #pragma unroll
        for (int i = 0; i < 4; ++i) {
            const int nr = i * 16 + tr;
            ushort4 u;
            u.x = f2bf(T[tc4 + 0][nr]); u.y = f2bf(T[tc4 + 1][nr]);
            u.z = f2bf(T[tc4 + 2][nr]); u.w = f2bf(T[tc4 + 3][nr]);
            *(ushort4*)(Wt + (size_t)(n0 + nr) * DMODEL + k0 + tc4) = u;
        }
    } else {
        // ---- x fp32 -> bf16 ----
        const int idx = ((bid - 4096) * 256 + tid) * 4;
        const float4 v = *(const float4*)(x + idx);
        ushort4 u;
        u.x = f2bf(v.x); u.y = f2bf(v.y); u.z = f2bf(v.z); u.w = f2bf(v.w);
        *(ushort4*)(xb + idx) = u;
    }
}

// ---------------------------------------------------------------------------
// Fused QKV GEMM — 128x128 tile, BK=64, 256 threads (4 waves, 2Mx2N).
// EXACT round-5/7 kernel (105.2 us, MfmaUtil 43%, conflicts 0). Constraint
// recorded from r6: b128 column-fragment reads need >=128-B LDS rows
// (BK>=64 for bf16); BK=32 is unfixably 8-way conflicted.
// LDS = 64 KB -> 2 blocks/CU. Grid 1536 = 6 exact rounds.
// ---------------------------------------------------------------------------
__global__ __launch_bounds__(256, 2) void qkv_gemm128_kernel(
    const unsigned short* __restrict__ A, const unsigned short* __restrict__ WtAll,
    const float* __restrict__ bq, const float* __restrict__ bk,
    const float* __restrict__ bv,
    unsigned short* __restrict__ Qb, unsigned short* __restrict__ Kb,
    unsigned short* __restrict__ Vt)
{
    constexpr int K  = DMODEL;   // 2048
    constexpr int NT = K / 64;   // 32 K-tiles

    __shared__ __align__(16) unsigned short As[2][128 * 64];   // 16 KB each
    __shared__ __align__(16) unsigned short Bs[2][128 * 64];   // 16 KB each

    const int tid  = threadIdx.x;
    const int lane = tid & 63;
    const int wave = tid >> 6;      // 0..3
    const int ln15 = lane & 15;
    const int quad = lane >> 4;
    const int wr   = wave >> 1;     // 0..1  (M half)
    const int wc   = wave & 1;      // 0..1  (N half)

    // XCD chunking: 1536 blocks, 192/XCD; by-inner so 4 concurrent blocks
    // share a B-tile; XCD k owns by 4k..4k+3 (A band 2 MB, L2-resident).
    const int xcd = blockIdx.x & 7;
    const int loc = blockIdx.x >> 3;       // 0..191
    const int bx  = loc >> 2;              // 0..47  N tile
    const int by  = xcd * 4 + (loc & 3);   // 0..31  M tile
    const int bm  = by * 128;
    const int bn  = bx * 128;              // 0..6016
    const int widx = bn >> 11;             // 0=Q 1=K 2=V
    const int bnl  = bn & 2047;

    const float* bias = widx == 0 ? bq : (widx == 1 ? bk : bv);

    // ---- staging: thread -> (row sr within 32-row unit, swizzled granule) ----
    const int sr = tid >> 3;                 // 0..31
    const int sg = (tid & 7) ^ (sr & 7);     // XOR swizzle (involution)
    const unsigned short* Ag = A     + (size_t)(bm + sr) * K + sg * 8;
    const unsigned short* Bg = WtAll + (size_t)(bn + sr) * K + sg * 8;

    // ---- ds_read offsets (ushort units); physical granule = logical ^ (row&7)
    const int swz0 = ((0 + quad) ^ (ln15 & 7)) * 8;   // ks=0
    const int swz1 = ((4 + quad) ^ (ln15 & 7)) * 8;   // ks=1
    const int arow = (wr * 64 + ln15) * 64;           // + mp*1024
    const int brow = (wc * 64 + ln15) * 64;           // + np*1024

#define STAGE_A(c, q, k0) async_load16(Ag + (size_t)(q) * 32 * K + (k0), \
                                       &As[c][(q) * 2048 + wave * 512])
#define STAGE_B(c, q, k0) async_load16(Bg + (size_t)(q) * 32 * K + (k0), \
                                       &Bs[c][(q) * 2048 + wave * 512])

    f32x4 acc[4][4];
    #pragma unroll
    for (int i = 0; i < 4; ++i)
        #pragma unroll
        for (int j = 0; j < 4; ++j) acc[i][j] = (f32x4){0.f, 0.f, 0.f, 0.f};

    // ---- prologue: tiles 0 and 1 fully staged (8 units each) ----
    STAGE_A(0, 0, 0); STAGE_A(0, 1, 0); STAGE_A(0, 2, 0); STAGE_A(0, 3, 0);
    STAGE_B(0, 0, 0); STAGE_B(0, 1, 0); STAGE_B(0, 2, 0); STAGE_B(0, 3, 0);
    STAGE_A(1, 0, 64); STAGE_A(1, 1, 64); STAGE_A(1, 2, 64); STAGE_A(1, 3, 64);
    STAGE_B(1, 0, 64); STAGE_B(1, 1, 64); STAGE_B(1, 2, 64); STAGE_B(1, 3, 64);
    asm volatile("s_waitcnt vmcnt(8)" ::: "memory");   // tile 0 landed
    __builtin_amdgcn_s_barrier();

    short8 af[4][2];
    short8 bfr[4][2];

    #pragma unroll 2
    for (int t = 0; t < NT; ++t) {
        const int c  = t & 1;
        const int k2 = (t + 2) * 64;
        const unsigned short* Ac = As[c];
        const unsigned short* Bc = Bs[c];

        // ---- phase 1: read ALL 16 frags; MFMA mt0-1 ----
        #pragma unroll
        for (int np = 0; np < 4; ++np) {
            bfr[np][0] = *(const short8*)(Bc + brow + np * 1024 + swz0);
            bfr[np][1] = *(const short8*)(Bc + brow + np * 1024 + swz1);
        }
        #pragma unroll
        for (int mp = 0; mp < 4; ++mp) {
            af[mp][0] = *(const short8*)(Ac + arow + mp * 1024 + swz0);
            af[mp][1] = *(const short8*)(Ac + arow + mp * 1024 + swz1);
        }
        __builtin_amdgcn_s_barrier();
        asm volatile("s_waitcnt lgkmcnt(0)" ::: "memory");
        __builtin_amdgcn_sched_barrier(0);
        __builtin_amdgcn_s_setprio(1);
        #pragma unroll
        for (int ks = 0; ks < 2; ++ks)
            #pragma unroll
            for (int mt = 0; mt < 2; ++mt)
                #pragma unroll
                for (int nt = 0; nt < 4; ++nt)
                    acc[mt][nt] = __builtin_amdgcn_mfma_f32_16x16x32_bf16(
                        af[mt][ks], bfr[nt][ks], acc[mt][nt], 0, 0, 0);
        __builtin_amdgcn_s_setprio(0);
        __builtin_amdgcn_s_barrier();

        // ---- phase 2: stage all 8 units of tile t+2; MFMA mt2-3 ----
        if (t + 2 < NT) {
            STAGE_A(c, 0, k2); STAGE_A(c, 1, k2);
            STAGE_A(c, 2, k2); STAGE_A(c, 3, k2);
            STAGE_B(c, 0, k2); STAGE_B(c, 1, k2);
            STAGE_B(c, 2, k2); STAGE_B(c, 3, k2);
        }
        __builtin_amdgcn_s_setprio(1);
        #pragma unroll
        for (int ks = 0; ks < 2; ++ks)
            #pragma unroll
            for (int mt = 2; mt < 4; ++mt)
                #pragma unroll
                for (int nt = 0; nt < 4; ++nt)
                    acc[mt][nt] = __builtin_amdgcn_mfma_f32_16x16x32_bf16(
                        af[mt][ks], bfr[nt][ks], acc[mt][nt], 0, 0, 0);
        __builtin_amdgcn_s_setprio(0);
        if (t + 2 < NT) { asm volatile("s_waitcnt vmcnt(8)" ::: "memory"); }
        else            { asm volatile("s_waitcnt vmcnt(0)" ::: "memory"); }
        __builtin_amdgcn_s_barrier();
    }

#undef STAGE_A
#undef STAGE_B

    // ---- epilogue ----
    if (widx == 2) {
        #pragma unroll
        for (int mp = 0; mp < 4; ++mp) {
            const int m0 = bm + wr * 64 + mp * 16 + quad * 4;
            const int bb = m0 >> 11;
            const int s0 = m0 & 2047;
            #pragma unroll
            for (int np = 0; np < 4; ++np) {
                const int col = bnl + wc * 64 + np * 16 + ln15;
                const float bvv = bias[col];
                ushort4 pk;
                pk.x = f2bf(acc[mp][np][0] + bvv);
                pk.y = f2bf(acc[mp][np][1] + bvv);
                pk.z = f2bf(acc[mp][np][2] + bvv);
                pk.w = f2bf(acc[mp][np][3] + bvv);
                *(ushort4*)(Vt + ((size_t)(bb * 16 + (col >> 7)) * 128 + (col & 127)) * SEQ + s0) = pk;
            }
        }
    } else {
        unsigned short* dst = widx ? Kb : Qb;
        #pragma unroll
        for (int mp = 0; mp < 4; ++mp)
            #pragma unroll
            for (int r = 0; r < 4; ++r) {
                const int row = bm + wr * 64 + mp * 16 + quad * 4 + r;
                #pragma unroll
                for (int np = 0; np < 4; ++np) {
                    const int col = bnl + wc * 64 + np * 16 + ln15;
                    dst[(size_t)row * DMODEL + col] = f2bf(acc[mp][np][r] + bias[col]);
                }
            }
    }
}

// ---------------------------------------------------------------------------
// Out-projection GEMM — 128x128, BK=64, 4 waves, LDS 64 KB -> 2 blocks/CU.
// Grid 512 = exactly 2 rounds. fp32 epilogue + bias. Unchanged from round 7;
// B operand now comes from Wt slot 3 (wo transposed upfront by prep_kernel).
// ---------------------------------------------------------------------------
__global__ __launch_bounds__(256, 2) void gemm_out128_kernel(
    const unsigned short* __restrict__ A, const unsigned short* __restrict__ Bt,
    const float* __restrict__ bias, float* __restrict__ C)
{
    constexpr int K  = DMODEL;   // 2048
    constexpr int N  = DMODEL;   // 2048
    constexpr int NT = K / 64;   // 32 K-tiles

    __shared__ __align__(16) unsigned short As[2][128 * 64];   // 16 KB each
    __shared__ __align__(16) unsigned short Bs[2][128 * 64];   // 16 KB each

    const int tid  = threadIdx.x;
    const int lane = tid & 63;
    const int wave = tid >> 6;      // 0..3
    const int ln15 = lane & 15;
    const int quad = lane >> 4;
    const int wr   = wave >> 1;     // 0..1  (M half)
    const int wc   = wave & 1;      // 0..1  (N half)

    // XCD chunking: 512 blocks, 64/XCD; by-inner (4 blocks share a B-tile)
    const int xcd = blockIdx.x & 7;
    const int loc = blockIdx.x >> 3;       // 0..63
    const int bx  = loc >> 2;              // 0..15  N tile
    const int by  = xcd * 4 + (loc & 3);   // 0..31  M tile
    const int bm  = by * 128;
    const int bn  = bx * 128;

    const int sr = tid >> 3;                 // 0..31
    const int sg = (tid & 7) ^ (sr & 7);     // XOR swizzle (involution)
    const unsigned short* Ag = A  + (size_t)(bm + sr) * K + sg * 8;
    const unsigned short* Bg = Bt + (size_t)(bn + sr) * K + sg * 8;

    const int swz0 = ((0 + quad) ^ (ln15 & 7)) * 8;   // ks=0
    const int swz1 = ((4 + quad) ^ (ln15 & 7)) * 8;   // ks=1
    const int arow = (wr * 64 + ln15) * 64;
    const int brow = (wc * 64 + ln15) * 64;

#define STAGE_A(c, q, k0) async_load16(Ag + (size_t)(q) * 32 * K + (k0), \
                                       &As[c][(q) * 2048 + wave * 512])
#define STAGE_B(c, q, k0) async_load16(Bg + (size_t)(q) * 32 * K + (k0), \
                                       &Bs[c][(q) * 2048 + wave * 512])

    f32x4 acc[4][4];
    #pragma unroll
    for (int i = 0; i < 4; ++i)
        #pragma unroll
        for (int j = 0; j < 4; ++j) acc[i][j] = (f32x4){0.f, 0.f, 0.f, 0.f};

    STAGE_A(0, 0, 0); STAGE_A(0, 1, 0); STAGE_A(0, 2, 0); STAGE_A(0, 3, 0);
    STAGE_B(0, 0, 0); STAGE_B(0, 1, 0); STAGE_B(0, 2, 0); STAGE_B(0, 3, 0);
    STAGE_A(1, 0, 64); STAGE_A(1, 1, 64); STAGE_A(1, 2, 64); STAGE_A(1, 3, 64);
    STAGE_B(1, 0, 64); STAGE_B(1, 1, 64); STAGE_B(1, 2, 64); STAGE_B(1, 3, 64);
    asm volatile("s_waitcnt vmcnt(8)" ::: "memory");
    __builtin_amdgcn_s_barrier();

    short8 af[4][2];
    short8 bfr[4][2];

    #pragma unroll 2
    for (int t = 0; t < NT; ++t) {
        const int c  = t & 1;
        const int k2 = (t + 2) * 64;
        const unsigned short* Ac = As[c];
        const unsigned short* Bc = Bs[c];

        #pragma unroll
        for (int np = 0; np < 4; ++np) {
            bfr[np][0] = *(const short8*)(Bc + brow + np * 1024 + swz0);
            bfr[np][1] = *(const short8*)(Bc + brow + np * 1024 + swz1);
        }
        #pragma unroll
        for (int mp = 0; mp < 4; ++mp) {
            af[mp][0] = *(const short8*)(Ac + arow + mp * 1024 + swz0);
            af[mp][1] = *(const short8*)(Ac + arow + mp * 1024 + swz1);
        }
        __builtin_amdgcn_s_barrier();
        asm volatile("s_waitcnt lgkmcnt(0)" ::: "memory");
        __builtin_amdgcn_sched_barrier(0);
        __builtin_amdgcn_s_setprio(1);
        #pragma unroll
        for (int ks = 0; ks < 2; ++ks)
            #pragma unroll
            for (int mt = 0; mt < 2; ++mt)
                #pragma unroll
                for (int nt = 0; nt < 4; ++nt)
                    acc[mt][nt] = __builtin_amdgcn_mfma_f32_16x16x32_bf16(
                        af[mt][ks], bfr[nt][ks], acc[mt][nt], 0, 0, 0);
        __builtin_amdgcn_s_setprio(0);
        __builtin_amdgcn_s_barrier();

        if (t + 2 < NT) {
            STAGE_A(c, 0, k2); STAGE_A(c, 1, k2);
            STAGE_A(c, 2, k2); STAGE_A(c, 3, k2);
            STAGE_B(c, 0, k2); STAGE_B(c, 1, k2);
            STAGE_B(c, 2, k2); STAGE_B(c, 3, k2);
        }
        __builtin_amdgcn_s_setprio(1);
        #pragma unroll
        for (int ks = 0; ks < 2; ++ks)
            #pragma unroll
            for (int mt = 2; mt < 4; ++mt)
                #pragma unroll
                for (int nt = 0; nt < 4; ++nt)
                    acc[mt][nt] = __builtin_amdgcn_mfma_f32_16x16x32_bf16(
                        af[mt][ks], bfr[nt][ks], acc[mt][nt], 0, 0, 0);
        __builtin_amdgcn_s_setprio(0);
        if (t + 2 < NT) { asm volatile("s_waitcnt vmcnt(8)" ::: "memory"); }
        else            { asm volatile("s_waitcnt vmcnt(0)" ::: "memory"); }
        __builtin_amdgcn_s_barrier();
    }

#undef STAGE_A
#undef STAGE_B

    #pragma unroll
    for (int mp = 0; mp < 4; ++mp)
        #pragma unroll
        for (int r = 0; r < 4; ++r) {
            const int row = bm + wr * 64 + mp * 16 + quad * 4 + r;
            #pragma unroll
            for (int np = 0; np < 4; ++np) {
                const int col = bn + wc * 64 + np * 16 + ln15;
                C[(size_t)row * N + col] = acc[mp][np][r] + bias[col];
            }
        }
}

// ---------------------------------------------------------------------------
// MFMA flash attention — LDS-staged, double-buffered, fast-path/diagonal
// split, XCD-pinned. 1024 single-qblk blocks, 4 blocks/CU, per-CU-balanced
// qblk permutation (sum == 62 per CU slot). Unchanged from round 5.
// ---------------------------------------------------------------------------
#define ATT_P_STRIDE 40

__global__ __launch_bounds__(256, 4) void attn_kernel(
    const unsigned short* __restrict__ Qb, const unsigned short* __restrict__ Kb,
    const unsigned short* __restrict__ Vt,   // [B*H][HDIM][SEQ]
    unsigned short* __restrict__ O)
{
    __shared__ __align__(16) unsigned short Ks[2][32 * 128];
    __shared__ __align__(16) unsigned short Vs[2][128 * 32];
    __shared__ __align__(16) unsigned short Pl[4 * 16 * ATT_P_STRIDE];

    const int tid  = threadIdx.x;
    const int lane = tid & 63;
    const int wave = tid >> 6;
    const int ln15 = lane & 15;
    const int quad = lane >> 4;

    // XCD pinning + per-CU load balance
    const int g  = blockIdx.x & 31;
    const int j  = blockIdx.x >> 5;        // 0..31
    const int r_ = j >> 3;
    const int c_ = j & 7;
    const int qblk = r_ == 0 ? 31 - c_ : (r_ == 1 ? 16 + c_ : (r_ == 2 ? 15 - c_ : c_));
    const int h = g & 15;
    const int b = g >> 4;

    const size_t rowbase = (size_t)b * SEQ;
    const size_t hoff    = (size_t)h * HDIM;
    const unsigned short* Kh  = Kb + rowbase * DMODEL + hoff;
    const unsigned short* Vth = Vt + (size_t)(b * NHEADS + h) * HDIM * SEQ;

    const float sc2     = 0.08838834764831845f * 1.4426950408889634f;
    const float slope2  = exp2f(-0.5f * (float)(h + 1)) * 1.4426950408889634f;
    const float slope16 = slope2 * 16.0f;
    const float slope32 = slope2 * 32.0f;

    // staging lane roles
    const int kq  = wave * 8 + (lane >> 4);
    const int ksl = lane & 15;
    const int dq  = wave * 32 + (lane >> 2);
    const int vsl = lane & 3;
    const int vsw = (ln15 >> 1) & 3;

    unsigned short* Pw = &Pl[wave * 16 * ATT_P_STRIDE];

    const int q0w  = qblk * 64 + wave * 16;
    const int nT   = 2 * qblk + 2;

    short8 qf[4];
    {
        const unsigned short* qp =
            Qb + (rowbase + q0w + ln15) * DMODEL + hoff + quad * 8;
        qf[0] = *(const short8*)(qp);
        qf[1] = *(const short8*)(qp + 32);
        qf[2] = *(const short8*)(qp + 64);
        qf[3] = *(const short8*)(qp + 96);
    }

    f32x4 acc[8];
    #pragma unroll
    for (int nt = 0; nt < 8; ++nt) acc[nt] = (f32x4){0.f, 0.f, 0.f, 0.f};
    float lsum[4] = {0.f, 0.f, 0.f, 0.f};

    // incremental ALiBi bias: c0[r] = slope2*(kb+ln15 - (q0w+quad*4+r))
    float c0[4];
    {
        const float base = slope2 * (float)(ln15 - q0w - quad * 4);
        #pragma unroll
        for (int r = 0; r < 4; ++r) c0[r] = base - slope2 * (float)r;
    }

    // ---- stage tile 0 into buffer 0 ----
    #pragma unroll
    for (int i = 0; i < 2; ++i) {
        const int k = kq + i * 4;
        async_load16(Kh + (size_t)k * DMODEL + (ksl ^ (k & 15)) * 8,
                     &Ks[0][(wave * 8 + i * 4) * 128]);
    }
    #pragma unroll
    for (int i = 0; i < 2; ++i) {
        const int d = dq + i * 16;
        async_load16(Vth + (size_t)d * SEQ + (vsl ^ ((d >> 1) & 3)) * 8,
                     &Vs[0][(wave * 32 + i * 16) * 32]);
    }
    __syncthreads();

    for (int t = 0; t < nT; ++t) {
        const int kb  = t * 32;
        const int buf = t & 1;

        if (t + 1 < nT) {
            const int kb1 = kb + 32;
            #pragma unroll
            for (int i = 0; i < 2; ++i) {
                const int k = kq + i * 4;
                async_load16(Kh + (size_t)(kb1 + k) * DMODEL + (ksl ^ (k & 15)) * 8,
                             &Ks[buf ^ 1][(wave * 8 + i * 4) * 128]);
            }
            #pragma unroll
            for (int i = 0; i < 2; ++i) {
                const int d = dq + i * 16;
                async_load16(Vth + (size_t)d * SEQ + kb1 + (vsl ^ ((d >> 1) & 3)) * 8,
                             &Vs[buf ^ 1][(wave * 32 + i * 16) * 32]);
            }
        }

        if (kb <= q0w + 15) {
            const unsigned short* KsB = Ks[buf];
            const unsigned short* VsB = Vs[buf];

            f32x4 s0 = (f32x4){0.f,0.f,0.f,0.f}, s1 = (f32x4){0.f,0.f,0.f,0.f};
            #pragma unroll
            for (int c = 0; c < 4; ++c) {
                const int slot = (c * 4 + quad) ^ ln15;
                short8 kf0 = *(const short8*)(&KsB[ln15 * 128 + slot * 8]);
                short8 kf1 = *(const short8*)(&KsB[(16 + ln15) * 128 + slot * 8]);
                s0 = __builtin_amdgcn_mfma_f32_16x16x32_bf16(qf[c], kf0, s0, 0, 0, 0);
                s1 = __builtin_amdgcn_mfma_f32_16x16x32_bf16(qf[c], kf1, s1, 0, 0, 0);
            }

            float p0[4], p1[4];
            if (kb + 31 <= q0w) {
                // fully unmasked fast path
                #pragma unroll
                for (int r = 0; r < 4; ++r) {
                    p0[r] = exp2f(fmaf(s0[r], sc2, c0[r]));
                    p1[r] = exp2f(fmaf(s1[r], sc2, c0[r] + slope16));
                    lsum[r] += p0[r] + p1[r];
                }
            } else {
                // diagonal tile: per-element causal mask
                #pragma unroll
                for (int r = 0; r < 4; ++r) {
                    const int qrow = q0w + quad * 4 + r;
                    const int k0i = kb + ln15;
                    const float e0 = exp2f(fmaf(s0[r], sc2, c0[r]));
                    const float e1 = exp2f(fmaf(s1[r], sc2, c0[r] + slope16));
                    p0[r] = (k0i      <= qrow) ? e0 : 0.f;
                    p1[r] = (k0i + 16 <= qrow) ? e1 : 0.f;
                    lsum[r] += p0[r] + p1[r];
                }
            }

            #pragma unroll
            for (int r = 0; r < 4; ++r) {
                Pw[(quad * 4 + r) * ATT_P_STRIDE + ln15]      = f2bf(p0[r]);
                Pw[(quad * 4 + r) * ATT_P_STRIDE + 16 + ln15] = f2bf(p1[r]);
            }
            __builtin_amdgcn_s_waitcnt(0xC07F);   // lgkmcnt(0)
            short8 pf = *(const short8*)(&Pw[ln15 * ATT_P_STRIDE + quad * 8]);

            #pragma unroll
            for (int nt = 0; nt < 8; ++nt) {
                short8 vf = *(const short8*)(
                    &VsB[(nt * 16 + ln15) * 32 + (quad ^ vsw) * 8]);
                acc[nt] = __builtin_amdgcn_mfma_f32_16x16x32_bf16(pf, vf, acc[nt], 0, 0, 0);
            }
        }

        #pragma unroll
        for (int r = 0; r < 4; ++r) c0[r] += slope32;
        __syncthreads();
    }

    #pragma unroll
    for (int r = 0; r < 4; ++r) {
        float l = lsum[r];
        l += __shfl_xor(l, 1, 64);
        l += __shfl_xor(l, 2, 64);
        l += __shfl_xor(l, 4, 64);
        l += __shfl_xor(l, 8, 64);
        const float inv = 1.0f / l;
        const size_t ob = (rowbase + q0w + quad * 4 + r) * DMODEL + hoff;
        #pragma unroll
        for (int nt = 0; nt < 8; ++nt)
            O[ob + nt * 16 + ln15] = f2bf(acc[nt][r] * inv);
    }
}

// ---------------------------------------------------------------------------
extern "C" void kernel_launch(void* const* d_in, const int* in_sizes, int n_in,
                              void* d_out, int out_size, void* d_ws, size_t ws_size,
                              hipStream_t stream)
{
    const float* x  = (const float*)d_in[0];
    const float* wq = (const float*)d_in[1];
    const float* bq = (const float*)d_in[2];
    const float* wk = (const float*)d_in[3];
    const float* bk = (const float*)d_in[4];
    const float* wv = (const float*)d_in[5];
    const float* bv = (const float*)d_in[6];
    const float* wo = (const float*)d_in[7];
    const float* bo = (const float*)d_in[8];
    float* out = (float*)d_out;

    const size_t bufElems = (size_t)MROWS * DMODEL;   // 8.39M
    unsigned short* Qb  = (unsigned short*)d_ws;
    unsigned short* Kb  = Qb + bufElems;
    unsigned short* Vtg = Kb + bufElems;      // V^T: [B*H][HDIM][SEQ]
    unsigned short* xb  = Vtg + bufElems;     // x bf16; later reused as Ob
    unsigned short* Ob  = xb;                 // alias (xb dead after QKV GEMM)
    unsigned short* Wt  = xb + bufElems;      // 4 slots of 2048*2048 bf16 (wq,wk,wv,wo)

    // one prep dispatch: 4 weight transposes + x convert (12288 blocks)
    prep_kernel<<<dim3(4096 + 8192), dim3(256), 0, stream>>>(
        x, wq, wk, wv, wo, xb, Wt);

    qkv_gemm128_kernel<<<dim3(1536), dim3(256), 0, stream>>>(
        xb, Wt, bq, bk, bv, Qb, Kb, Vtg);

    attn_kernel<<<dim3(1024), dim3(256), 0, stream>>>(Qb, Kb, Vtg, Ob);

    gemm_out128_kernel<<<dim3(512), dim3(256), 0, stream>>>(
        Ob, Wt + (size_t)3 * DMODEL * DMODEL, bo, out);
}